// Round 10
// baseline (320.849 us; speedup 1.0000x reference)
//
#include <hip/hip_runtime.h>
#include <hip/hip_bf16.h>

#define DEVI __device__ __forceinline__

typedef __bf16 bf16x8_t __attribute__((ext_vector_type(8)));
typedef float f32x4_t __attribute__((ext_vector_type(4)));
typedef unsigned int u32;
typedef u32 u32x4_t __attribute__((ext_vector_type(4)));
typedef unsigned short u16;

// RNE fp32 -> bf16
DEVI u16 f2bf(float f) {
  u32 u = __builtin_bit_cast(u32, f);
  u = (u + 0x7fffu + ((u >> 16) & 1u)) >> 16;
  return (u16)u;
}

DEVI void gload_lds16(const void* g, void* l) {
  __builtin_amdgcn_global_load_lds((const __attribute__((address_space(1))) u32*)g,
                                   (__attribute__((address_space(3))) u32*)l, 16, 0, 0);
}

// ---------------- fp32 -> bf16 bulk convert ----------------
__global__ void cvt_kernel(const float* __restrict__ src, u16* __restrict__ dst, int n4) {
  int i = blockIdx.x * blockDim.x + threadIdx.x;
  int stride = gridDim.x * blockDim.x;
  for (; i < n4; i += stride) {
    float4 f = reinterpret_cast<const float4*>(src)[i];
    ushort4 o;
    o.x = f2bf(f.x); o.y = f2bf(f.y); o.z = f2bf(f.z); o.w = f2bf(f.w);
    reinterpret_cast<ushort4*>(dst)[i] = o;
  }
}

__global__ void cvt4_kernel(const float* __restrict__ s0, const float* __restrict__ s1,
                            const float* __restrict__ s2, const float* __restrict__ s3,
                            u16* __restrict__ w0, u16* __restrict__ w1,
                            u16* __restrict__ w2, u16* __restrict__ w3, int n4) {
  const float* src = (blockIdx.y == 0) ? s0 : (blockIdx.y == 1) ? s1 : (blockIdx.y == 2) ? s2 : s3;
  u16* dst = (blockIdx.y == 0) ? w0 : (blockIdx.y == 1) ? w1 : (blockIdx.y == 2) ? w2 : w3;
  int i = blockIdx.x * blockDim.x + threadIdx.x;
  int stride = gridDim.x * blockDim.x;
  for (; i < n4; i += stride) {
    float4 f = reinterpret_cast<const float4*>(src)[i];
    ushort4 o;
    o.x = f2bf(f.x); o.y = f2bf(f.y); o.z = f2bf(f.z); o.w = f2bf(f.w);
    reinterpret_cast<ushort4*>(dst)[i] = o;
  }
}

// ---------------- m97-style 128x128 GEMM mainloop ----------------
DEVI void stage_tile32(const u16* __restrict__ g, int ldg, u16* lds, int wid, int lane) {
#pragma unroll
  for (int i = 0; i < 2; ++i) {
    int idx = wid * 128 + i * 64 + lane;
    int row = idx >> 2, seg = idx & 3;
    gload_lds16(g + row * ldg + seg * 8, lds + (wid * 128 + i * 64) * 8);
  }
}

DEVI void gemm_mainloop(const u16* __restrict__ A, const u16* __restrict__ W, int Kdim,
                        int m0, int n0, int wid, int lane,
                        u16 (*As)[128 * 32], u16 (*Bs)[128 * 32], f32x4_t acc[4][4]) {
#pragma unroll
  for (int m = 0; m < 4; ++m)
#pragma unroll
    for (int n = 0; n < 4; ++n)
#pragma unroll
      for (int r = 0; r < 4; ++r) acc[m][n][r] = 0.f;

  const int NK = Kdim >> 5;
  stage_tile32(A + m0 * Kdim, Kdim, As[0], wid, lane);
  stage_tile32(W + n0 * Kdim, Kdim, Bs[0], wid, lane);
  __syncthreads();

  const int wr = wid >> 1, wc = wid & 1;
  const int r16 = lane & 15, koff = (lane >> 4) * 8;
  for (int kt = 0; kt < NK; ++kt) {
    int cur = kt & 1;
    if (kt + 1 < NK) {
      stage_tile32(A + m0 * Kdim + (kt + 1) * 32, Kdim, As[cur ^ 1], wid, lane);
      stage_tile32(W + n0 * Kdim + (kt + 1) * 32, Kdim, Bs[cur ^ 1], wid, lane);
    }
    bf16x8_t af[4], bf[4];
#pragma unroll
    for (int m = 0; m < 4; ++m)
      af[m] = *reinterpret_cast<const bf16x8_t*>(&As[cur][(wr * 64 + m * 16 + r16) * 32 + koff]);
#pragma unroll
    for (int n = 0; n < 4; ++n)
      bf[n] = *reinterpret_cast<const bf16x8_t*>(&Bs[cur][(wc * 64 + n * 16 + r16) * 32 + koff]);
#pragma unroll
    for (int m = 0; m < 4; ++m)
#pragma unroll
      for (int n = 0; n < 4; ++n)
        acc[m][n] = __builtin_amdgcn_mfma_f32_16x16x32_bf16(af[m], bf[n], acc[m][n], 0, 0, 0);
    __syncthreads();
  }
}

// ---------------- QKV projection ----------------
// GRID SWAP (T1): blockIdx.x = m-tile (64), blockIdx.y = n-tile (8) so that
// XCD id = linear%8 = m%8 -> all 8 n-blocks sharing the same A(X) rows land on
// one XCD; A panel becomes L2-resident (read once from L3 instead of 8x).
// z=0: Q scaled by 0.125*log2(e), layout [bh][s][d]; z=1: K; z=2: V^T slot-permuted.
__global__ __launch_bounds__(256) void qkv_gemm(
    const u16* __restrict__ Xb,
    const u16* __restrict__ Wqb, const u16* __restrict__ Wkb, const u16* __restrict__ Wvb,
    const float* __restrict__ bq, const float* __restrict__ bk, const float* __restrict__ bv,
    u16* __restrict__ Qo, u16* __restrict__ Ko, u16* __restrict__ Vto) {
  __shared__ u16 As[2][128 * 32];
  __shared__ u16 Bs[2][128 * 32];
  const int tid = threadIdx.x, lane = tid & 63, wid = tid >> 6;
  const int z = blockIdx.z;
  const u16* W = (z == 0) ? Wqb : (z == 1) ? Wkb : Wvb;
  const float* bias = (z == 0) ? bq : (z == 1) ? bk : bv;
  const int m0 = blockIdx.x * 128, n0 = blockIdx.y * 128;  // swapped roles

  f32x4_t acc[4][4];
  gemm_mainloop(Xb, W, 1024, m0, n0, wid, lane, As, Bs, acc);

  const int wr = wid >> 1, wc = wid & 1;
  const int rbase = m0 + wr * 64 + ((lane >> 4) << 2);
#pragma unroll
  for (int n = 0; n < 4; ++n) {
    int col = n0 + wc * 64 + n * 16 + (lane & 15);  // h*64+d
    float bia = bias[col];
    int h = col >> 6, d = col & 63;
#pragma unroll
    for (int m = 0; m < 4; ++m) {
      int row0 = rbase + m * 16;
      int b = row0 >> 11, s0 = row0 & 2047;
      int bh = b * 16 + h;
      if (z == 2) {
        ushort4 pk;
        pk.x = f2bf(acc[m][n][0] + bia);
        pk.y = f2bf(acc[m][n][1] + bia);
        pk.z = f2bf(acc[m][n][2] + bia);
        pk.w = f2bf(acc[m][n][3] + bia);
        int cv = (s0 >> 2) & 15;
        int cs = ((cv >> 3) << 3) | ((cv & 3) << 1) | ((cv >> 2) & 1);
        int s0p = (s0 & ~63) | (cs << 2);
        *reinterpret_cast<ushort4*>(&Vto[bh * 131072 + d * 2048 + s0p]) = pk;
      } else {
        u16* P = (z == 0) ? Qo : Ko;
        float sc = (z == 0) ? 0.18033688f : 1.0f;  // Q: 1/8 * log2(e)
#pragma unroll
        for (int r = 0; r < 4; ++r)
          P[bh * 131072 + (s0 + r) * 64 + d] = f2bf((acc[m][n][r] + bia) * sc);
      }
    }
  }
}

// ---------------- flash attention (swapped-QK^T, in-register softmax) ----------------
// MT=4: each wave owns 64 q-rows (block = 256 q-rows), amortizing the shared
// K/V LDS reads over 2x the output vs MT=2 (the 16 ds_read_b128/tile are the
// per-CU bottleneck after R8). grid 512 = 8 qt x 64 bh; bijective XCD decode
// keeps all 8 q-tiles of a head on one XCD. T5 setprio around MFMA clusters.
__global__ __launch_bounds__(256) void attn_kernel(const u16* __restrict__ Qb,
                                                   const u16* __restrict__ Kb,
                                                   const u16* __restrict__ Vtb,
                                                   u16* __restrict__ Ob) {
  __shared__ u16 Ks[2][64 * 64];
  __shared__ u16 Vs[2][64 * 64];
  const int tid = threadIdx.x, lane = tid & 63, wid = tid >> 6;
  const int bid = blockIdx.x;
  const int bh = (bid & 7) * 8 + (bid >> 6);  // XCD=bid%8 fixed per bh
  const int qt = (bid >> 3) & 7;
  const int b = bh >> 4, h = bh & 15;
  const u16* Qh = Qb + bh * 131072;
  const u16* Kh = Kb + bh * 131072;
  const u16* Vh = Vtb + bh * 131072;  // [d][kv-slot], slot-permuted
  const int q0 = qt * 256 + wid * 64;
  const int r16 = lane & 15, g4 = lane >> 4;

  // Q fragments in registers (B-operand: col=q=r16, k=d): 4 x 16 q-rows
  bf16x8_t qf[4][2];
#pragma unroll
  for (int mt = 0; mt < 4; ++mt)
#pragma unroll
    for (int kk = 0; kk < 2; ++kk)
      qf[mt][kk] = *reinterpret_cast<const bf16x8_t*>(
          &Qh[(q0 + mt * 16 + r16) * 64 + kk * 32 + g4 * 8]);

  const f32x4_t zero4 = {0.f, 0.f, 0.f, 0.f};
  const u32x4_t onesu = {0x3f803f80u, 0x3f803f80u, 0x3f803f80u, 0x3f803f80u};
  const bf16x8_t ones8 = __builtin_bit_cast(bf16x8_t, onesu);

  f32x4_t oacc[4][4];
  f32x4_t sumacc[4];
#pragma unroll
  for (int mt = 0; mt < 4; ++mt) {
#pragma unroll
    for (int dt = 0; dt < 4; ++dt)
#pragma unroll
      for (int r = 0; r < 4; ++r) oacc[mt][dt][r] = 0.f;
#pragma unroll
    for (int r = 0; r < 4; ++r) sumacc[mt][r] = 0.f;
  }

#define ATTN_STAGE(buf, t_)                                                     \
  {                                                                             \
    _Pragma("unroll") for (int i = 0; i < 2; ++i) {                             \
      int idx = wid * 128 + i * 64 + lane;                                      \
      int row = idx >> 3, seg = idx & 7;                                        \
      int sseg = seg ^ (row & 7);                                               \
      gload_lds16(Kh + ((t_) * 64 + row) * 64 + sseg * 8,                       \
                  (u16*)Ks[buf] + (wid * 128 + i * 64) * 8);                    \
      gload_lds16(Vh + row * 2048 + (t_) * 64 + sseg * 8,                       \
                  (u16*)Vs[buf] + (wid * 128 + i * 64) * 8);                    \
    }                                                                           \
  }

  ATTN_STAGE(0, 0)
  __syncthreads();

  for (int t = 0; t < 32; ++t) {
    int cur = t & 1;
    if (t + 1 < 32) ATTN_STAGE(cur ^ 1, t + 1)

    const char* KsB = (const char*)Ks[cur];
    const char* VsB = (const char*)Vs[cur];

    // ---- swapped QK^T: C[kv][q]; lane: kv=g4*4+r, q=r16 ----
    f32x4_t sacc[4][4];
    __builtin_amdgcn_s_setprio(1);
#pragma unroll
    for (int nt = 0; nt < 4; ++nt) {
      int row = nt * 16 + r16;
      int bo0 = (row * 128 + 0 * 64 + g4 * 16) ^ ((row & 7) << 4);
      int bo1 = (row * 128 + 1 * 64 + g4 * 16) ^ ((row & 7) << 4);
      bf16x8_t kf0 = *reinterpret_cast<const bf16x8_t*>(KsB + bo0);
      bf16x8_t kf1 = *reinterpret_cast<const bf16x8_t*>(KsB + bo1);
#pragma unroll
      for (int mt = 0; mt < 4; ++mt) {
        sacc[mt][nt] = __builtin_amdgcn_mfma_f32_16x16x32_bf16(kf0, qf[mt][0], zero4, 0, 0, 0);
        sacc[mt][nt] = __builtin_amdgcn_mfma_f32_16x16x32_bf16(kf1, qf[mt][1], sacc[mt][nt], 0, 0, 0);
      }
    }
    __builtin_amdgcn_s_setprio(0);

    // ---- softmax numerator: exp2, RTZ pack, per-mt MFMA row-sum ----
    // (RTZ bias cancels: denominator sums the same rounded p-hat.)
    bf16x8_t pfr[4][2];
#pragma unroll
    for (int mt = 0; mt < 4; ++mt) {
      u32 dw[8];
#pragma unroll
      for (int nt = 0; nt < 4; ++nt) {
        float e0 = __builtin_amdgcn_exp2f(sacc[mt][nt][0]);
        float e1 = __builtin_amdgcn_exp2f(sacc[mt][nt][1]);
        float e2 = __builtin_amdgcn_exp2f(sacc[mt][nt][2]);
        float e3 = __builtin_amdgcn_exp2f(sacc[mt][nt][3]);
        dw[nt * 2]     = (__builtin_bit_cast(u32, e0) >> 16) |
                         (__builtin_bit_cast(u32, e1) & 0xffff0000u);
        dw[nt * 2 + 1] = (__builtin_bit_cast(u32, e2) >> 16) |
                         (__builtin_bit_cast(u32, e3) & 0xffff0000u);
      }
      u32x4_t lo = {dw[0], dw[1], dw[2], dw[3]};
      u32x4_t hi = {dw[4], dw[5], dw[6], dw[7]};
      pfr[mt][0] = __builtin_bit_cast(bf16x8_t, lo);
      pfr[mt][1] = __builtin_bit_cast(bf16x8_t, hi);
      sumacc[mt] = __builtin_amdgcn_mfma_f32_16x16x32_bf16(pfr[mt][0], ones8, sumacc[mt], 0, 0, 0);
      sumacc[mt] = __builtin_amdgcn_mfma_f32_16x16x32_bf16(pfr[mt][1], ones8, sumacc[mt], 0, 0, 0);
    }

    // ---- PV: oacc[mt][dt] += P * V ----
    __builtin_amdgcn_s_setprio(1);
#pragma unroll
    for (int dt = 0; dt < 4; ++dt) {
      int drow = dt * 16 + r16;
#pragma unroll
      for (int kk = 0; kk < 2; ++kk) {
        int bo_ = (drow * 128 + kk * 64 + g4 * 16) ^ ((drow & 7) << 4);
        bf16x8_t vf = *reinterpret_cast<const bf16x8_t*>(VsB + bo_);
#pragma unroll
        for (int mt = 0; mt < 4; ++mt)
          oacc[mt][dt] = __builtin_amdgcn_mfma_f32_16x16x32_bf16(pfr[mt][kk], vf, oacc[mt][dt], 0, 0, 0);
      }
    }
    __builtin_amdgcn_s_setprio(0);
    __syncthreads();
  }

  // ---- normalize + store O[b*S+s][h*64+d] ----
#pragma unroll
  for (int mt = 0; mt < 4; ++mt) {
    float rinv[4];
#pragma unroll
    for (int r = 0; r < 4; ++r) rinv[r] = 1.0f / sumacc[mt][r];
#pragma unroll
    for (int dt = 0; dt < 4; ++dt) {
      int d = dt * 16 + r16;
#pragma unroll
      for (int r = 0; r < 4; ++r) {
        int srow = q0 + mt * 16 + g4 * 4 + r;
        Ob[(b * 2048 + srow) * 1024 + h * 64 + d] = f2bf(oacc[mt][dt][r] * rinv[r]);
      }
    }
  }
}

// ---------------- output projection (fp32 out + bias; grid-swapped like qkv) ----------------
__global__ __launch_bounds__(256) void out_gemm(const u16* __restrict__ Ob,
                                                const u16* __restrict__ Wob,
                                                const float* __restrict__ bo,
                                                float* __restrict__ out) {
  __shared__ u16 As[2][128 * 32];
  __shared__ u16 Bs[2][128 * 32];
  const int tid = threadIdx.x, lane = tid & 63, wid = tid >> 6;
  const int m0 = blockIdx.x * 128, n0 = blockIdx.y * 128;  // swapped roles
  f32x4_t acc[4][4];
  gemm_mainloop(Ob, Wob, 1024, m0, n0, wid, lane, As, Bs, acc);
  const int wr = wid >> 1, wc = wid & 1;
#pragma unroll
  for (int n = 0; n < 4; ++n) {
    int col = n0 + wc * 64 + n * 16 + (lane & 15);
    float bia = bo[col];
#pragma unroll
    for (int m = 0; m < 4; ++m) {
      int row0 = m0 + wr * 64 + m * 16 + ((lane >> 4) << 2);
#pragma unroll
      for (int r = 0; r < 4; ++r) out[(row0 + r) * 1024 + col] = acc[m][n][r] + bia;
    }
  }
}

// ---------------- launcher ----------------
// ws layout (72 MB peak; Ob aliases Xb since X is dead after qkv_gemm):
//   [0,16M)   Xb [8192][1024] bf16   -> later Ob [8192][1024] bf16
//   [16M,24M) Wqb/Wkb/Wvb/Wob (2 MB each)
//   [24M,40M) Qb  [64][2048][64] bf16 (pre-scaled 0.125*log2e)
//   [40M,56M) Kb  [64][2048][64] bf16
//   [56M,72M) Vtb [64][64][2048] bf16 (transposed, kv-slot-permuted per 64-tile)
extern "C" void kernel_launch(void* const* d_in, const int* in_sizes, int n_in,
                              void* d_out, int out_size, void* d_ws, size_t ws_size,
                              hipStream_t stream) {
  const float* X  = (const float*)d_in[0];
  const float* Wq = (const float*)d_in[1];
  const float* bq = (const float*)d_in[2];
  const float* Wk = (const float*)d_in[3];
  const float* bk = (const float*)d_in[4];
  const float* Wv = (const float*)d_in[5];
  const float* bv = (const float*)d_in[6];
  const float* Wo = (const float*)d_in[7];
  const float* bo = (const float*)d_in[8];
  float* out = (float*)d_out;

  char* ws = (char*)d_ws;
  u16* Xb  = (u16*)(ws + 0);
  u16* Ob  = (u16*)(ws + 0);  // aliases Xb (X dead after qkv_gemm)
  u16* Wqb = (u16*)(ws + 16777216);
  u16* Wkb = (u16*)(ws + 18874368);
  u16* Wvb = (u16*)(ws + 20971520);
  u16* Wob = (u16*)(ws + 23068672);
  u16* Qb  = (u16*)(ws + 25165824);
  u16* Kb  = (u16*)(ws + 41943040);
  u16* Vtb = (u16*)(ws + 58720256);

  hipLaunchKernelGGL(cvt_kernel, dim3(2048), dim3(256), 0, stream, X, Xb, 2097152);
  hipLaunchKernelGGL(cvt4_kernel, dim3(256, 4), dim3(256), 0, stream,
                     Wq, Wk, Wv, Wo, Wqb, Wkb, Wvb, Wob, 262144);

  hipLaunchKernelGGL(qkv_gemm, dim3(64, 8, 3), dim3(256), 0, stream,
                     Xb, Wqb, Wkb, Wvb, bq, bk, bv, Qb, Kb, Vtb);
  hipLaunchKernelGGL(attn_kernel, dim3(512), dim3(256), 0, stream, Qb, Kb, Vtb, Ob);
  hipLaunchKernelGGL(out_gemm, dim3(64, 8), dim3(256), 0, stream, Ob, Wob, bo, out);
}

// Round 13
// 288.341 us; speedup vs baseline: 1.1127x; 1.1127x over previous
//
#include <hip/hip_runtime.h>
#include <hip/hip_bf16.h>

#define DEVI __device__ __forceinline__

typedef __bf16 bf16x8_t __attribute__((ext_vector_type(8)));
typedef float f32x4_t __attribute__((ext_vector_type(4)));
typedef unsigned int u32;
typedef u32 u32x4_t __attribute__((ext_vector_type(4)));
typedef unsigned short u16;

// RNE fp32 -> bf16
DEVI u16 f2bf(float f) {
  u32 u = __builtin_bit_cast(u32, f);
  u = (u + 0x7fffu + ((u >> 16) & 1u)) >> 16;
  return (u16)u;
}

DEVI void gload_lds16(const void* g, void* l) {
  __builtin_amdgcn_global_load_lds((const __attribute__((address_space(1))) u32*)g,
                                   (__attribute__((address_space(3))) u32*)l, 16, 0, 0);
}

// ---------------- fp32 -> bf16 bulk convert ----------------
__global__ void cvt_kernel(const float* __restrict__ src, u16* __restrict__ dst, int n4) {
  int i = blockIdx.x * blockDim.x + threadIdx.x;
  int stride = gridDim.x * blockDim.x;
  for (; i < n4; i += stride) {
    float4 f = reinterpret_cast<const float4*>(src)[i];
    ushort4 o;
    o.x = f2bf(f.x); o.y = f2bf(f.y); o.z = f2bf(f.z); o.w = f2bf(f.w);
    reinterpret_cast<ushort4*>(dst)[i] = o;
  }
}

__global__ void cvt4_kernel(const float* __restrict__ s0, const float* __restrict__ s1,
                            const float* __restrict__ s2, const float* __restrict__ s3,
                            u16* __restrict__ w0, u16* __restrict__ w1,
                            u16* __restrict__ w2, u16* __restrict__ w3, int n4) {
  const float* src = (blockIdx.y == 0) ? s0 : (blockIdx.y == 1) ? s1 : (blockIdx.y == 2) ? s2 : s3;
  u16* dst = (blockIdx.y == 0) ? w0 : (blockIdx.y == 1) ? w1 : (blockIdx.y == 2) ? w2 : w3;
  int i = blockIdx.x * blockDim.x + threadIdx.x;
  int stride = gridDim.x * blockDim.x;
  for (; i < n4; i += stride) {
    float4 f = reinterpret_cast<const float4*>(src)[i];
    ushort4 o;
    o.x = f2bf(f.x); o.y = f2bf(f.y); o.z = f2bf(f.z); o.w = f2bf(f.w);
    reinterpret_cast<ushort4*>(dst)[i] = o;
  }
}

// ---------------- m97-style 128x128 GEMM mainloop ----------------
DEVI void stage_tile32(const u16* __restrict__ g, int ldg, u16* lds, int wid, int lane) {
#pragma unroll
  for (int i = 0; i < 2; ++i) {
    int idx = wid * 128 + i * 64 + lane;
    int row = idx >> 2, seg = idx & 3;
    gload_lds16(g + row * ldg + seg * 8, lds + (wid * 128 + i * 64) * 8);
  }
}

DEVI void gemm_mainloop(const u16* __restrict__ A, const u16* __restrict__ W, int Kdim,
                        int m0, int n0, int wid, int lane,
                        u16 (*As)[128 * 32], u16 (*Bs)[128 * 32], f32x4_t acc[4][4]) {
#pragma unroll
  for (int m = 0; m < 4; ++m)
#pragma unroll
    for (int n = 0; n < 4; ++n)
#pragma unroll
      for (int r = 0; r < 4; ++r) acc[m][n][r] = 0.f;

  const int NK = Kdim >> 5;
  stage_tile32(A + m0 * Kdim, Kdim, As[0], wid, lane);
  stage_tile32(W + n0 * Kdim, Kdim, Bs[0], wid, lane);
  __syncthreads();

  const int wr = wid >> 1, wc = wid & 1;
  const int r16 = lane & 15, koff = (lane >> 4) * 8;
  for (int kt = 0; kt < NK; ++kt) {
    int cur = kt & 1;
    if (kt + 1 < NK) {
      stage_tile32(A + m0 * Kdim + (kt + 1) * 32, Kdim, As[cur ^ 1], wid, lane);
      stage_tile32(W + n0 * Kdim + (kt + 1) * 32, Kdim, Bs[cur ^ 1], wid, lane);
    }
    bf16x8_t af[4], bf[4];
#pragma unroll
    for (int m = 0; m < 4; ++m)
      af[m] = *reinterpret_cast<const bf16x8_t*>(&As[cur][(wr * 64 + m * 16 + r16) * 32 + koff]);
#pragma unroll
    for (int n = 0; n < 4; ++n)
      bf[n] = *reinterpret_cast<const bf16x8_t*>(&Bs[cur][(wc * 64 + n * 16 + r16) * 32 + koff]);
#pragma unroll
    for (int m = 0; m < 4; ++m)
#pragma unroll
      for (int n = 0; n < 4; ++n)
        acc[m][n] = __builtin_amdgcn_mfma_f32_16x16x32_bf16(af[m], bf[n], acc[m][n], 0, 0, 0);
    __syncthreads();
  }
}

// ---------------- QKV projection ----------------
// GRID SWAP (kept from R10, measured neutral): blockIdx.x = m-tile so XCD = m%8;
// A panel shared by the 8 n-blocks stays on one XCD L2.
// z=0: Q scaled by 0.125*log2(e), layout [bh][s][d]; z=1: K; z=2: V^T slot-permuted.
__global__ __launch_bounds__(256) void qkv_gemm(
    const u16* __restrict__ Xb,
    const u16* __restrict__ Wqb, const u16* __restrict__ Wkb, const u16* __restrict__ Wvb,
    const float* __restrict__ bq, const float* __restrict__ bk, const float* __restrict__ bv,
    u16* __restrict__ Qo, u16* __restrict__ Ko, u16* __restrict__ Vto) {
  __shared__ u16 As[2][128 * 32];
  __shared__ u16 Bs[2][128 * 32];
  const int tid = threadIdx.x, lane = tid & 63, wid = tid >> 6;
  const int z = blockIdx.z;
  const u16* W = (z == 0) ? Wqb : (z == 1) ? Wkb : Wvb;
  const float* bias = (z == 0) ? bq : (z == 1) ? bk : bv;
  const int m0 = blockIdx.x * 128, n0 = blockIdx.y * 128;

  f32x4_t acc[4][4];
  gemm_mainloop(Xb, W, 1024, m0, n0, wid, lane, As, Bs, acc);

  const int wr = wid >> 1, wc = wid & 1;
  const int rbase = m0 + wr * 64 + ((lane >> 4) << 2);
#pragma unroll
  for (int n = 0; n < 4; ++n) {
    int col = n0 + wc * 64 + n * 16 + (lane & 15);  // h*64+d
    float bia = bias[col];
    int h = col >> 6, d = col & 63;
#pragma unroll
    for (int m = 0; m < 4; ++m) {
      int row0 = rbase + m * 16;
      int b = row0 >> 11, s0 = row0 & 2047;
      int bh = b * 16 + h;
      if (z == 2) {
        ushort4 pk;
        pk.x = f2bf(acc[m][n][0] + bia);
        pk.y = f2bf(acc[m][n][1] + bia);
        pk.z = f2bf(acc[m][n][2] + bia);
        pk.w = f2bf(acc[m][n][3] + bia);
        int cv = (s0 >> 2) & 15;
        int cs = ((cv >> 3) << 3) | ((cv & 3) << 1) | ((cv >> 2) & 1);
        int s0p = (s0 & ~63) | (cs << 2);
        *reinterpret_cast<ushort4*>(&Vto[bh * 131072 + d * 2048 + s0p]) = pk;
      } else {
        u16* P = (z == 0) ? Qo : Ko;
        float sc = (z == 0) ? 0.18033688f : 1.0f;  // Q: 1/8 * log2(e)
#pragma unroll
        for (int r = 0; r < 4; ++r)
          P[bh * 131072 + (s0 + r) * 64 + d] = f2bf((acc[m][n][r] + bia) * sc);
      }
    }
  }
}

// ---------------- flash attention (swapped-QK^T, in-register softmax) ----------------
// MT=2 (proven 105.7 us; MT=4 regressed via occupancy cliff, R10).
// __launch_bounds__(256,3): force VGPR<=170 so 3 waves/SIMD (12/CU) fit —
// total need ~156 (84 arch + 72 acc) fits; HW ran only 2 without the bound.
// T5 setprio around MFMA clusters. grid 1024; XCD-bijective decode.
__global__ __launch_bounds__(256, 3) void attn_kernel(const u16* __restrict__ Qb,
                                                      const u16* __restrict__ Kb,
                                                      const u16* __restrict__ Vtb,
                                                      u16* __restrict__ Ob) {
  __shared__ u16 Ks[2][64 * 64];
  __shared__ u16 Vs[2][64 * 64];
  const int tid = threadIdx.x, lane = tid & 63, wid = tid >> 6;
  const int bid = blockIdx.x;
  const int bh = (bid & 7) * 8 + (bid >> 7);  // bijective; XCD=bid%8 fixed per bh
  const int qt = (bid >> 3) & 15;
  const int b = bh >> 4, h = bh & 15;
  const u16* Qh = Qb + bh * 131072;
  const u16* Kh = Kb + bh * 131072;
  const u16* Vh = Vtb + bh * 131072;  // [d][kv-slot], slot-permuted
  const int q0 = qt * 128 + wid * 32;
  const int r16 = lane & 15, g4 = lane >> 4;

  // Q fragments in registers (B-operand: col=q=r16, k=d)
  bf16x8_t qf[2][2];
#pragma unroll
  for (int mt = 0; mt < 2; ++mt)
#pragma unroll
    for (int kk = 0; kk < 2; ++kk)
      qf[mt][kk] = *reinterpret_cast<const bf16x8_t*>(
          &Qh[(q0 + mt * 16 + r16) * 64 + kk * 32 + g4 * 8]);

  const f32x4_t zero4 = {0.f, 0.f, 0.f, 0.f};
  const u32x4_t onesu = {0x3f803f80u, 0x3f803f80u, 0x3f803f80u, 0x3f803f80u};
  const bf16x8_t ones8 = __builtin_bit_cast(bf16x8_t, onesu);

  f32x4_t oacc[2][4];
  f32x4_t sumacc[2];
#pragma unroll
  for (int mt = 0; mt < 2; ++mt) {
#pragma unroll
    for (int dt = 0; dt < 4; ++dt)
#pragma unroll
      for (int r = 0; r < 4; ++r) oacc[mt][dt][r] = 0.f;
#pragma unroll
    for (int r = 0; r < 4; ++r) sumacc[mt][r] = 0.f;
  }

#define ATTN_STAGE(buf, t_)                                                     \
  {                                                                             \
    _Pragma("unroll") for (int i = 0; i < 2; ++i) {                             \
      int idx = wid * 128 + i * 64 + lane;                                      \
      int row = idx >> 3, seg = idx & 7;                                        \
      int sseg = seg ^ (row & 7);                                               \
      gload_lds16(Kh + ((t_) * 64 + row) * 64 + sseg * 8,                       \
                  (u16*)Ks[buf] + (wid * 128 + i * 64) * 8);                    \
      gload_lds16(Vh + row * 2048 + (t_) * 64 + sseg * 8,                       \
                  (u16*)Vs[buf] + (wid * 128 + i * 64) * 8);                    \
    }                                                                           \
  }

  ATTN_STAGE(0, 0)
  __syncthreads();

  for (int t = 0; t < 32; ++t) {
    int cur = t & 1;
    if (t + 1 < 32) ATTN_STAGE(cur ^ 1, t + 1)

    const char* KsB = (const char*)Ks[cur];
    const char* VsB = (const char*)Vs[cur];

    // ---- swapped QK^T: C[kv][q]; lane: kv=g4*4+r, q=r16 ----
    f32x4_t sacc[2][4];
    __builtin_amdgcn_s_setprio(1);
#pragma unroll
    for (int nt = 0; nt < 4; ++nt) {
      int row = nt * 16 + r16;
      int bo0 = (row * 128 + 0 * 64 + g4 * 16) ^ ((row & 7) << 4);
      int bo1 = (row * 128 + 1 * 64 + g4 * 16) ^ ((row & 7) << 4);
      bf16x8_t kf0 = *reinterpret_cast<const bf16x8_t*>(KsB + bo0);
      bf16x8_t kf1 = *reinterpret_cast<const bf16x8_t*>(KsB + bo1);
#pragma unroll
      for (int mt = 0; mt < 2; ++mt) {
        sacc[mt][nt] = __builtin_amdgcn_mfma_f32_16x16x32_bf16(kf0, qf[mt][0], zero4, 0, 0, 0);
        sacc[mt][nt] = __builtin_amdgcn_mfma_f32_16x16x32_bf16(kf1, qf[mt][1], sacc[mt][nt], 0, 0, 0);
      }
    }
    __builtin_amdgcn_s_setprio(0);

    // ---- softmax numerator: exp2 (log2e pre-folded into Q), RTZ pack ----
    // RTZ bias cancels: denominator sums the SAME rounded p-hat via ones-MFMA.
    bf16x8_t pfr[2][2];
#pragma unroll
    for (int mt = 0; mt < 2; ++mt) {
      u32 dw[8];
#pragma unroll
      for (int nt = 0; nt < 4; ++nt) {
        float e0 = __builtin_amdgcn_exp2f(sacc[mt][nt][0]);
        float e1 = __builtin_amdgcn_exp2f(sacc[mt][nt][1]);
        float e2 = __builtin_amdgcn_exp2f(sacc[mt][nt][2]);
        float e3 = __builtin_amdgcn_exp2f(sacc[mt][nt][3]);
        dw[nt * 2]     = (__builtin_bit_cast(u32, e0) >> 16) |
                         (__builtin_bit_cast(u32, e1) & 0xffff0000u);
        dw[nt * 2 + 1] = (__builtin_bit_cast(u32, e2) >> 16) |
                         (__builtin_bit_cast(u32, e3) & 0xffff0000u);
      }
      u32x4_t lo = {dw[0], dw[1], dw[2], dw[3]};
      u32x4_t hi = {dw[4], dw[5], dw[6], dw[7]};
      pfr[mt][0] = __builtin_bit_cast(bf16x8_t, lo);
      pfr[mt][1] = __builtin_bit_cast(bf16x8_t, hi);
      sumacc[mt] = __builtin_amdgcn_mfma_f32_16x16x32_bf16(pfr[mt][0], ones8, sumacc[mt], 0, 0, 0);
      sumacc[mt] = __builtin_amdgcn_mfma_f32_16x16x32_bf16(pfr[mt][1], ones8, sumacc[mt], 0, 0, 0);
    }

    // ---- PV: oacc[mt][dt] += P * V ----
    __builtin_amdgcn_s_setprio(1);
#pragma unroll
    for (int dt = 0; dt < 4; ++dt) {
      int drow = dt * 16 + r16;
#pragma unroll
      for (int kk = 0; kk < 2; ++kk) {
        int bo_ = (drow * 128 + kk * 64 + g4 * 16) ^ ((drow & 7) << 4);
        bf16x8_t vf = *reinterpret_cast<const bf16x8_t*>(VsB + bo_);
#pragma unroll
        for (int mt = 0; mt < 2; ++mt)
          oacc[mt][dt] = __builtin_amdgcn_mfma_f32_16x16x32_bf16(pfr[mt][kk], vf, oacc[mt][dt], 0, 0, 0);
      }
    }
    __builtin_amdgcn_s_setprio(0);
    __syncthreads();
  }

  // ---- normalize + store O[b*S+s][h*64+d] ----
  // sumacc[mt][r] is the row-sum for q-local = g4*4+r (col-replicated across r16).
#pragma unroll
  for (int mt = 0; mt < 2; ++mt) {
    float rinv[4];
#pragma unroll
    for (int r = 0; r < 4; ++r) rinv[r] = 1.0f / sumacc[mt][r];
#pragma unroll
    for (int dt = 0; dt < 4; ++dt) {
      int d = dt * 16 + r16;
#pragma unroll
      for (int r = 0; r < 4; ++r) {
        int srow = q0 + mt * 16 + g4 * 4 + r;
        Ob[(b * 2048 + srow) * 1024 + h * 64 + d] = f2bf(oacc[mt][dt][r] * rinv[r]);
      }
    }
  }
}

// ---------------- output projection (fp32 out + bias; grid-swapped like qkv) ----------------
__global__ __launch_bounds__(256) void out_gemm(const u16* __restrict__ Ob,
                                                const u16* __restrict__ Wob,
                                                const float* __restrict__ bo,
                                                float* __restrict__ out) {
  __shared__ u16 As[2][128 * 32];
  __shared__ u16 Bs[2][128 * 32];
  const int tid = threadIdx.x, lane = tid & 63, wid = tid >> 6;
  const int m0 = blockIdx.x * 128, n0 = blockIdx.y * 128;
  f32x4_t acc[4][4];
  gemm_mainloop(Ob, Wob, 1024, m0, n0, wid, lane, As, Bs, acc);
  const int wr = wid >> 1, wc = wid & 1;
#pragma unroll
  for (int n = 0; n < 4; ++n) {
    int col = n0 + wc * 64 + n * 16 + (lane & 15);
    float bia = bo[col];
#pragma unroll
    for (int m = 0; m < 4; ++m) {
      int row0 = m0 + wr * 64 + m * 16 + ((lane >> 4) << 2);
#pragma unroll
      for (int r = 0; r < 4; ++r) out[(row0 + r) * 1024 + col] = acc[m][n][r] + bia;
    }
  }
}

// ---------------- launcher ----------------
// ws layout (72 MB peak; Ob aliases Xb since X is dead after qkv_gemm):
//   [0,16M)   Xb [8192][1024] bf16   -> later Ob [8192][1024] bf16
//   [16M,24M) Wqb/Wkb/Wvb/Wob (2 MB each)
//   [24M,40M) Qb  [64][2048][64] bf16 (pre-scaled 0.125*log2e)
//   [40M,56M) Kb  [64][2048][64] bf16
//   [56M,72M) Vtb [64][64][2048] bf16 (transposed, kv-slot-permuted per 64-tile)
extern "C" void kernel_launch(void* const* d_in, const int* in_sizes, int n_in,
                              void* d_out, int out_size, void* d_ws, size_t ws_size,
                              hipStream_t stream) {
  const float* X  = (const float*)d_in[0];
  const float* Wq = (const float*)d_in[1];
  const float* bq = (const float*)d_in[2];
  const float* Wk = (const float*)d_in[3];
  const float* bk = (const float*)d_in[4];
  const float* Wv = (const float*)d_in[5];
  const float* bv = (const float*)d_in[6];
  const float* Wo = (const float*)d_in[7];
  const float* bo = (const float*)d_in[8];
  float* out = (float*)d_out;

  char* ws = (char*)d_ws;
  u16* Xb  = (u16*)(ws + 0);
  u16* Ob  = (u16*)(ws + 0);  // aliases Xb (X dead after qkv_gemm)
  u16* Wqb = (u16*)(ws + 16777216);
  u16* Wkb = (u16*)(ws + 18874368);
  u16* Wvb = (u16*)(ws + 20971520);
  u16* Wob = (u16*)(ws + 23068672);
  u16* Qb  = (u16*)(ws + 25165824);
  u16* Kb  = (u16*)(ws + 41943040);
  u16* Vtb = (u16*)(ws + 58720256);

  hipLaunchKernelGGL(cvt_kernel, dim3(2048), dim3(256), 0, stream, X, Xb, 2097152);
  hipLaunchKernelGGL(cvt4_kernel, dim3(256, 4), dim3(256), 0, stream,
                     Wq, Wk, Wv, Wo, Wqb, Wkb, Wvb, Wob, 262144);

  hipLaunchKernelGGL(qkv_gemm, dim3(64, 8, 3), dim3(256), 0, stream,
                     Xb, Wqb, Wkb, Wvb, bq, bk, bv, Qb, Kb, Vtb);
  hipLaunchKernelGGL(attn_kernel, dim3(1024), dim3(256), 0, stream, Qb, Kb, Vtb, Ob);
  hipLaunchKernelGGL(out_gemm, dim3(64, 8), dim3(256), 0, stream, Ob, Wob, bo, out);
}